// Round 8
// baseline (260.610 us; speedup 1.0000x reference)
//
#include <hip/hip_runtime.h>

// Partitioned MHA: x(4,2048,1024) fp32 -> (out_c, out_p) each (4,2048,512) fp32.
// R8: k_attn FROZEN (R7-verified, 132.8us). ONE change: XCD-affinity block
// swizzles (T1) in k_qkv and k_proj so all blocks sharing an input slice land
// on one XCD's L2 (x was re-fetched 16x, O 8x). No math/layout changes.

typedef __attribute__((ext_vector_type(8))) short bf16x8;
typedef __attribute__((ext_vector_type(4))) float f32x4;
typedef unsigned short u16;

#define QSCALE 0.18033688011112042f  // (1/sqrt(64)) * log2(e): max-free softmax uses exp2(s)

__device__ __forceinline__ u16 f2bf(float f){
  unsigned u = __builtin_bit_cast(unsigned, f);
  u += 0x7FFFu + ((u >> 16) & 1u);
  return (u16)(u >> 16);
}

__device__ __forceinline__ unsigned cvtpk(float lo, float hi){
  unsigned r;
  asm("v_cvt_pk_bf16_f32 %0, %1, %2" : "=v"(r) : "v"(lo), "v"(hi));
  return r;
}

__device__ __forceinline__ void gload16(const void* g, void* l){
  __builtin_amdgcn_global_load_lds(
    (const __attribute__((address_space(1))) unsigned*)g,
    (__attribute__((address_space(3))) unsigned*)l, 16, 0, 0);
}

// ---------- x fp32 -> bf16 ----------
__global__ __launch_bounds__(256) void k_cvt_x(const float4* __restrict__ x, uint2* __restrict__ xb){
  int i = blockIdx.x*256 + threadIdx.x;
  float4 v = x[i];
  uint2 o;
  o.x = (unsigned)f2bf(v.x) | ((unsigned)f2bf(v.y) << 16);
  o.y = (unsigned)f2bf(v.z) | ((unsigned)f2bf(v.w) << 16);
  xb[i] = o;
}

// ---------- repack w_qkv (16,512,3,32)x2 fp32 -> wt[part*16+h][ca=96][f=512] bf16 ----------
__global__ __launch_bounds__(256) void k_repack_qkv(const float* __restrict__ wc, const float* __restrict__ wp,
                                                    u16* __restrict__ wt){
  int i = blockIdx.x*256 + threadIdx.x;
  int f  = i & 511;
  int ca = (i >> 9) % 96;
  int ph = (i >> 9) / 96;
  const float* src = (ph < 16) ? wc : wp;
  wt[i] = f2bf(src[(ph & 15)*49152 + f*96 + ca]);
}

// ---------- repack w_o (16,32,512)x2 fp32 -> wot[part][f=512][k=512] bf16 ----------
__global__ __launch_bounds__(256) void k_repack_wo(const float* __restrict__ wc, const float* __restrict__ wp,
                                                   u16* __restrict__ wt){
  int i = blockIdx.x*256 + threadIdx.x;
  int k = i & 511;
  int f = (i >> 9) & 511;
  int part = i >> 18;
  const float* src = part ? wp : wc;
  wt[i] = f2bf(src[k*512 + f]);
}

// ---------- QKV projection: 256-token blocks, wave owns 64 rows ----------
// grid 1024 linear, XCD-affine: all 32 ph-blocks of a token tile on one XCD.
// Q,K as [bh][2048][64] bf16 (Q pre-scaled); V^T as [bh][64][2048] bf16.
__global__ __launch_bounds__(256) void k_qkv(const u16* __restrict__ xb, const u16* __restrict__ wt,
                                             u16* __restrict__ Q, u16* __restrict__ K, u16* __restrict__ VT){
  const int lane = threadIdx.x & 63, wv = threadIdx.x >> 6;
  const int lg = lane >> 4, li = lane & 15;
  const int blk = blockIdx.x;
  const int xcd = blk & 7, idx = blk >> 3;         // 128 blocks per XCD
  const int tt  = (idx >> 5)*8 + xcd;              // token tile [0,32), 4 per XCD
  const int ph  = idx & 31;                        // all 32 ph share tt's x-slice
  const int row0 = tt*256 + wv*64;
  const int part = ph >> 4, h = ph & 15;

  f32x4 acc[4][6] = {};
  const u16* wbase = wt + (size_t)ph*96*512;
  #pragma unroll 2
  for (int ks = 0; ks < 16; ++ks){
    bf16x8 a[4], b[6];
    #pragma unroll
    for (int m=0;m<4;++m)
      a[m] = *(const bf16x8*)(xb + (size_t)(row0 + m*16 + li)*1024 + part*512 + ks*32 + lg*8);
    #pragma unroll
    for (int n=0;n<6;++n)
      b[n] = *(const bf16x8*)(wbase + (size_t)(n*16 + li)*512 + ks*32 + lg*8);
    #pragma unroll
    for (int m=0;m<4;++m)
      #pragma unroll
      for (int n=0;n<6;++n)
        acc[m][n] = __builtin_amdgcn_mfma_f32_16x16x32_bf16(a[m], b[n], acc[m][n], 0, 0, 0);
  }

  const int b_ = row0 >> 11;
  const int bh = b_*16 + h;
  const int tl0 = (row0 & 2047) + lg*4;
  #pragma unroll
  for (int m=0;m<4;++m){
    #pragma unroll
    for (int n=0;n<6;++n){
      const int c = n >> 1;
      const int af = part*32 + (n & 1)*16 + li;
      if (c == 2){
        uint2 pk;
        pk.x = (unsigned)f2bf(acc[m][n][0]) | ((unsigned)f2bf(acc[m][n][1]) << 16);
        pk.y = (unsigned)f2bf(acc[m][n][2]) | ((unsigned)f2bf(acc[m][n][3]) << 16);
        *(uint2*)(VT + (size_t)(bh*64 + af)*2048 + tl0 + m*16) = pk;
      } else {
        u16* dst = (c == 0) ? Q : K;
        const float sc = (c == 0) ? QSCALE : 1.0f;
        #pragma unroll
        for (int r=0;r<4;++r){
          int tl = tl0 + m*16 + r;
          dst[((size_t)bh*2048 + tl)*64 + af] = f2bf(acc[m][n][r] * sc);
        }
      }
    }
  }
}

// ---------- flash attention (max-free softmax; swapped QK^T, packed P writes) ----------
// grid 1024 (XCD-swizzled -> bh, q-tile). 4 waves * 32 q-rows. KV tile = 32 keys.
// LDS: K[3]x4KB @0 | V[3]x4KB @12288 | P 4x[32][40] u16 @24576. Total 34816 B.
#define NKT 64
#define PLD 40
__global__ __launch_bounds__(256) void k_attn(const u16* __restrict__ Q, const u16* __restrict__ K,
                                              const u16* __restrict__ VT, u16* __restrict__ O){
  __shared__ __align__(16) char smem[34816];
  const int lane = threadIdx.x & 63, w = threadIdx.x >> 6;
  const int lg = lane >> 4, li = lane & 15;
  const int swz = (blockIdx.x & 7)*128 + (blockIdx.x >> 3);   // XCD-contiguous
  const int bh = swz >> 4, qt = swz & 15;
  const int q0 = qt*128 + w*32;

  const char* Kg = (const char*)(K  + (size_t)bh*131072);
  const char* Vg = (const char*)(VT + (size_t)bh*131072);
  const u16*  Qb = Q + (size_t)bh*131072;
  u16* pw = (u16*)(smem + 24576) + w*(32*PLD);

  const unsigned ksrc = (unsigned)((w*8 + (lane>>3))*128 + (((lane&7) ^ (lane>>3)) << 4));
  const unsigned vsrc0 = (unsigned)((w*16 + (lane>>2))*4096 + (((lane&3) ^ ((lane>>2)&3)) << 4));
  const unsigned ldst = (unsigned)(w*1024);

  const unsigned kc0 = (unsigned)(((     lg) ^ (li&7)) << 4);
  const unsigned kc1 = (unsigned)(((4 +  lg) ^ (li&7)) << 4);
  const unsigned vc  = (unsigned)(((lg) ^ (li&3)) << 4);

  bf16x8 aq[2][2];
  #pragma unroll
  for (int m=0;m<2;++m)
    #pragma unroll
    for (int kd=0;kd<2;++kd)
      aq[m][kd] = *(const bf16x8*)(Qb + (size_t)(q0 + m*16 + li)*64 + kd*32 + lg*8);

  const short one_bf = (short)0x3F80;
  bf16x8 ones = {one_bf,one_bf,one_bf,one_bf,one_bf,one_bf,one_bf,one_bf};

  f32x4 o[2][4] = {};
  f32x4 ls[2] = {};

  auto COMPUTE = [&](int cbuf){
    const char* sK = smem + cbuf*4096;
    const char* sV = smem + 12288 + cbuf*4096;
    #pragma unroll
    for (int n=0;n<2;++n){
      bf16x8 bk0 = *(const bf16x8*)(sK + (n*16 + li)*128 + kc0);
      bf16x8 bk1 = *(const bf16x8*)(sK + (n*16 + li)*128 + kc1);
      #pragma unroll
      for (int m=0;m<2;++m){
        f32x4 s = {0.f,0.f,0.f,0.f};
        s = __builtin_amdgcn_mfma_f32_16x16x32_bf16(bk0, aq[m][0], s, 0, 0, 0);
        s = __builtin_amdgcn_mfma_f32_16x16x32_bf16(bk1, aq[m][1], s, 0, 0, 0);
        float p0 = __builtin_exp2f(s[0]);
        float p1 = __builtin_exp2f(s[1]);
        float p2 = __builtin_exp2f(s[2]);
        float p3 = __builtin_exp2f(s[3]);
        uint2 pk;
        pk.x = cvtpk(p0, p1);
        pk.y = cvtpk(p2, p3);
        *(uint2*)(pw + (size_t)(m*16 + li)*PLD + n*16 + lg*4) = pk;
      }
    }
    bf16x8 pa0 = *(const bf16x8*)(pw + (size_t)(     li)*PLD + lg*8);
    bf16x8 pa1 = *(const bf16x8*)(pw + (size_t)(16 + li)*PLD + lg*8);
    __builtin_amdgcn_s_setprio(1);
    #pragma unroll
    for (int nd=0;nd<4;++nd){
      bf16x8 bv = *(const bf16x8*)(sV + (nd*16 + li)*64 + vc);
      o[0][nd] = __builtin_amdgcn_mfma_f32_16x16x32_bf16(pa0, bv, o[0][nd], 0, 0, 0);
      o[1][nd] = __builtin_amdgcn_mfma_f32_16x16x32_bf16(pa1, bv, o[1][nd], 0, 0, 0);
    }
    ls[0] = __builtin_amdgcn_mfma_f32_16x16x32_bf16(pa0, ones, ls[0], 0, 0, 0);
    ls[1] = __builtin_amdgcn_mfma_f32_16x16x32_bf16(pa1, ones, ls[1], 0, 0, 0);
    __builtin_amdgcn_s_setprio(0);
  };

  gload16(Kg + ksrc,          smem + ldst);
  gload16(Vg + vsrc0,         smem + 12288 + ldst);
  gload16(Kg + 4096u + ksrc,  smem + 4096 + ldst);
  gload16(Vg + 64u + vsrc0,   smem + 12288 + 4096 + ldst);
  asm volatile("s_waitcnt vmcnt(2)" ::: "memory");
  __builtin_amdgcn_s_barrier();

  int cb = 0;
  for (int kt = 0; kt < NKT-2; ++kt){
    int sb = cb + 2; if (sb >= 3) sb -= 3;
    gload16(Kg + (kt+2)*4096u + ksrc, smem + sb*4096 + ldst);
    gload16(Vg + (kt+2)*64u + vsrc0,  smem + 12288 + sb*4096 + ldst);
    COMPUTE(cb);
    asm volatile("s_waitcnt vmcnt(2)" ::: "memory");
    __builtin_amdgcn_s_barrier();
    cb = (cb+1 == 3) ? 0 : cb+1;
  }
  COMPUTE(cb);
  asm volatile("s_waitcnt vmcnt(0)" ::: "memory");
  __builtin_amdgcn_s_barrier();
  cb = (cb+1 == 3) ? 0 : cb+1;
  COMPUTE(cb);

  const int b_ = bh >> 4, h = bh & 15;
  #pragma unroll
  for (int m=0;m<2;++m){
    #pragma unroll
    for (int r=0;r<4;++r){
      float linv = 1.0f / ls[m][r];
      int t = q0 + m*16 + lg*4 + r;
      #pragma unroll
      for (int nd=0;nd<4;++nd)
        O[((size_t)b_*2048 + t)*1024 + h*64 + nd*16 + li] = f2bf(o[m][nd][r] * linv);
    }
  }
}

// ---------- output projection ----------
// grid 512 linear, XCD-affine: 8 col-tiles of a row-tile share the O slice in L2.
__global__ __launch_bounds__(256) void k_proj(const u16* __restrict__ O, const u16* __restrict__ wot,
                                              float* __restrict__ out){
  const int lane = threadIdx.x & 63, wv = threadIdx.x >> 6;
  const int lg = lane >> 4, li = lane & 15;
  const int blk = blockIdx.x;
  const int xcd = blk & 7, idx = blk >> 3;       // 64 blocks per XCD
  const int rowTile = (idx >> 3)*8 + xcd;        // [0,64), 8 per XCD
  const int colTile = idx & 7;                   // 8 col-tiles share row slice
  const int row0 = rowTile*128 + wv*32;
  const int col0 = colTile*128;
  const int part = col0 >> 9;
  const int f0 = col0 & 511;

  f32x4 acc[2][8] = {};
  #pragma unroll 4
  for (int ks = 0; ks < 16; ++ks){
    bf16x8 a[2];
    #pragma unroll
    for (int m=0;m<2;++m)
      a[m] = *(const bf16x8*)(O + (size_t)(row0 + m*16 + li)*1024 + ks*64 + part*32 + lg*8);
    #pragma unroll
    for (int n=0;n<8;++n){
      bf16x8 b = *(const bf16x8*)(wot + (size_t)part*262144 + (size_t)(f0 + n*16 + li)*512 + ks*32 + lg*8);
      #pragma unroll
      for (int m=0;m<2;++m)
        acc[m][n] = __builtin_amdgcn_mfma_f32_16x16x32_bf16(a[m], b, acc[m][n], 0, 0, 0);
    }
  }
  float* ob = out + (size_t)part*(8192u*512u);
  #pragma unroll
  for (int m=0;m<2;++m)
    #pragma unroll
    for (int n=0;n<8;++n)
      #pragma unroll
      for (int r=0;r<4;++r)
        ob[(size_t)(row0 + m*16 + lg*4 + r)*512 + f0 + n*16 + li] = acc[m][n][r];
}

extern "C" void kernel_launch(void* const* d_in, const int* in_sizes, int n_in,
                              void* d_out, int out_size, void* d_ws, size_t ws_size,
                              hipStream_t stream){
  const float* x   = (const float*)d_in[0];
  const float* wqc = (const float*)d_in[1];
  const float* wqp = (const float*)d_in[2];
  const float* woc = (const float*)d_in[3];
  const float* wop = (const float*)d_in[4];

  char* ws = (char*)d_ws;
  u16* xb  = (u16*)(ws);
  u16* Q   = (u16*)(ws + 16777216);
  u16* K   = (u16*)(ws + 2*16777216);
  u16* VT  = (u16*)(ws + 3*16777216);
  u16* wqt = (u16*)(ws + 4*16777216);
  u16* wot = (u16*)(ws + 4*16777216 + 3145728);
  u16* O   = xb;   // xb dead after k_qkv
  float* out = (float*)d_out;

  k_cvt_x     <<<8192, 256, 0, stream>>>((const float4*)x, (uint2*)xb);
  k_repack_qkv<<<6144, 256, 0, stream>>>(wqc, wqp, wqt);
  k_repack_wo <<<2048, 256, 0, stream>>>(woc, wop, wot);
  k_qkv       <<<1024, 256, 0, stream>>>(xb, wqt, Q, K, VT);
  k_attn      <<<1024, 256, 0, stream>>>(Q, K, VT, O);
  k_proj      <<<512,  256, 0, stream>>>(O, wot, out);
}

// Round 9
// 244.638 us; speedup vs baseline: 1.0653x; 1.0653x over previous
//
#include <hip/hip_runtime.h>

// Partitioned MHA: x(4,2048,1024) fp32 -> (out_c, out_p) each (4,2048,512) fp32.
// R9: k_attn software-pipelined — iteration kt does QK(kt+1) then PV(kt) (P in
// ping-pong wave-private LDS buffers), so exp2/cvtpk/P-write run in the MFMA
// shadow instead of on the serial chain. P math/rounding bit-identical to
// R7/R8 (absmax must stay 1.2207e-4). K/V dbuf staged 1 ahead, vmcnt(0)+raw
// barrier per iter. launch_bounds(256,4) pins VGPR<=128 (4 blocks/CU).

typedef __attribute__((ext_vector_type(8))) short bf16x8;
typedef __attribute__((ext_vector_type(4))) float f32x4;
typedef unsigned short u16;

#define QSCALE 0.18033688011112042f  // (1/sqrt(64)) * log2(e): max-free softmax uses exp2(s)

__device__ __forceinline__ u16 f2bf(float f){
  unsigned u = __builtin_bit_cast(unsigned, f);
  u += 0x7FFFu + ((u >> 16) & 1u);
  return (u16)(u >> 16);
}

__device__ __forceinline__ unsigned cvtpk(float lo, float hi){
  unsigned r;
  asm("v_cvt_pk_bf16_f32 %0, %1, %2" : "=v"(r) : "v"(lo), "v"(hi));
  return r;
}

__device__ __forceinline__ void gload16(const void* g, void* l){
  __builtin_amdgcn_global_load_lds(
    (const __attribute__((address_space(1))) unsigned*)g,
    (__attribute__((address_space(3))) unsigned*)l, 16, 0, 0);
}

// ---------- x fp32 -> bf16 ----------
__global__ __launch_bounds__(256) void k_cvt_x(const float4* __restrict__ x, uint2* __restrict__ xb){
  int i = blockIdx.x*256 + threadIdx.x;
  float4 v = x[i];
  uint2 o;
  o.x = (unsigned)f2bf(v.x) | ((unsigned)f2bf(v.y) << 16);
  o.y = (unsigned)f2bf(v.z) | ((unsigned)f2bf(v.w) << 16);
  xb[i] = o;
}

// ---------- repack w_qkv (16,512,3,32)x2 fp32 -> wt[part*16+h][ca=96][f=512] bf16 ----------
__global__ __launch_bounds__(256) void k_repack_qkv(const float* __restrict__ wc, const float* __restrict__ wp,
                                                    u16* __restrict__ wt){
  int i = blockIdx.x*256 + threadIdx.x;
  int f  = i & 511;
  int ca = (i >> 9) % 96;
  int ph = (i >> 9) / 96;
  const float* src = (ph < 16) ? wc : wp;
  wt[i] = f2bf(src[(ph & 15)*49152 + f*96 + ca]);
}

// ---------- repack w_o (16,32,512)x2 fp32 -> wot[part][f=512][k=512] bf16 ----------
__global__ __launch_bounds__(256) void k_repack_wo(const float* __restrict__ wc, const float* __restrict__ wp,
                                                   u16* __restrict__ wt){
  int i = blockIdx.x*256 + threadIdx.x;
  int k = i & 511;
  int f = (i >> 9) & 511;
  int part = i >> 18;
  const float* src = part ? wp : wc;
  wt[i] = f2bf(src[k*512 + f]);
}

// ---------- QKV projection: 256-token blocks, wave owns 64 rows (R8, XCD-affine) ----------
__global__ __launch_bounds__(256) void k_qkv(const u16* __restrict__ xb, const u16* __restrict__ wt,
                                             u16* __restrict__ Q, u16* __restrict__ K, u16* __restrict__ VT){
  const int lane = threadIdx.x & 63, wv = threadIdx.x >> 6;
  const int lg = lane >> 4, li = lane & 15;
  const int blk = blockIdx.x;
  const int xcd = blk & 7, idx = blk >> 3;
  const int tt  = (idx >> 5)*8 + xcd;
  const int ph  = idx & 31;
  const int row0 = tt*256 + wv*64;
  const int part = ph >> 4, h = ph & 15;

  f32x4 acc[4][6] = {};
  const u16* wbase = wt + (size_t)ph*96*512;
  #pragma unroll 2
  for (int ks = 0; ks < 16; ++ks){
    bf16x8 a[4], b[6];
    #pragma unroll
    for (int m=0;m<4;++m)
      a[m] = *(const bf16x8*)(xb + (size_t)(row0 + m*16 + li)*1024 + part*512 + ks*32 + lg*8);
    #pragma unroll
    for (int n=0;n<6;++n)
      b[n] = *(const bf16x8*)(wbase + (size_t)(n*16 + li)*512 + ks*32 + lg*8);
    #pragma unroll
    for (int m=0;m<4;++m)
      #pragma unroll
      for (int n=0;n<6;++n)
        acc[m][n] = __builtin_amdgcn_mfma_f32_16x16x32_bf16(a[m], b[n], acc[m][n], 0, 0, 0);
  }

  const int b_ = row0 >> 11;
  const int bh = b_*16 + h;
  const int tl0 = (row0 & 2047) + lg*4;
  #pragma unroll
  for (int m=0;m<4;++m){
    #pragma unroll
    for (int n=0;n<6;++n){
      const int c = n >> 1;
      const int af = part*32 + (n & 1)*16 + li;
      if (c == 2){
        uint2 pk;
        pk.x = (unsigned)f2bf(acc[m][n][0]) | ((unsigned)f2bf(acc[m][n][1]) << 16);
        pk.y = (unsigned)f2bf(acc[m][n][2]) | ((unsigned)f2bf(acc[m][n][3]) << 16);
        *(uint2*)(VT + (size_t)(bh*64 + af)*2048 + tl0 + m*16) = pk;
      } else {
        u16* dst = (c == 0) ? Q : K;
        const float sc = (c == 0) ? QSCALE : 1.0f;
        #pragma unroll
        for (int r=0;r<4;++r){
          int tl = tl0 + m*16 + r;
          dst[((size_t)bh*2048 + tl)*64 + af] = f2bf(acc[m][n][r] * sc);
        }
      }
    }
  }
}

// ---------- flash attention (max-free softmax; pipelined QK(kt+1) || PV(kt)) ----------
// grid 1024 (XCD-swizzled). 4 waves * 32 q-rows. KV tile = 32 keys.
// LDS: K0@0 K1@4096 | V0@8192 V1@12288 | P 4 waves x 2 copies x [32][40] u16
// @16384 (wave stride 5120, copy stride 2560). Total 36864 B.
#define NKT 64
#define PLD 40
__global__ __launch_bounds__(256, 4) void k_attn(const u16* __restrict__ Q, const u16* __restrict__ K,
                                                 const u16* __restrict__ VT, u16* __restrict__ O){
  __shared__ __align__(16) char smem[36864];
  const int lane = threadIdx.x & 63, w = threadIdx.x >> 6;
  const int lg = lane >> 4, li = lane & 15;
  const int swz = (blockIdx.x & 7)*128 + (blockIdx.x >> 3);   // XCD-contiguous
  const int bh = swz >> 4, qt = swz & 15;
  const int q0 = qt*128 + w*32;

  const char* Kg = (const char*)(K  + (size_t)bh*131072);
  const char* Vg = (const char*)(VT + (size_t)bh*131072);
  const u16*  Qb = Q + (size_t)bh*131072;
  u16* pw = (u16*)(smem + 16384) + w*2560;      // + copy*1280 (u16 units)

  const unsigned ksrc = (unsigned)((w*8 + (lane>>3))*128 + (((lane&7) ^ (lane>>3)) << 4));
  const unsigned vsrc0 = (unsigned)((w*16 + (lane>>2))*4096 + (((lane&3) ^ ((lane>>2)&3)) << 4));
  const unsigned ldst = (unsigned)(w*1024);

  const unsigned kc0 = (unsigned)(((     lg) ^ (li&7)) << 4);
  const unsigned kc1 = (unsigned)(((4 +  lg) ^ (li&7)) << 4);
  const unsigned vc  = (unsigned)(((lg) ^ (li&3)) << 4);

  bf16x8 aq[2][2];
  #pragma unroll
  for (int m=0;m<2;++m)
    #pragma unroll
    for (int kd=0;kd<2;++kd)
      aq[m][kd] = *(const bf16x8*)(Qb + (size_t)(q0 + m*16 + li)*64 + kd*32 + lg*8);

  const short one_bf = (short)0x3F80;
  bf16x8 ones = {one_bf,one_bf,one_bf,one_bf,one_bf,one_bf,one_bf,one_bf};

  f32x4 o[2][4] = {};
  f32x4 ls[2] = {};

  // QK(t) from K-LDS buffer kb, exp2+cvtpk, write P into pbuf copy pc
  auto QKEXP = [&](const char* sK, u16* pW){
    #pragma unroll
    for (int n=0;n<2;++n){
      bf16x8 bk0 = *(const bf16x8*)(sK + (n*16 + li)*128 + kc0);
      bf16x8 bk1 = *(const bf16x8*)(sK + (n*16 + li)*128 + kc1);
      #pragma unroll
      for (int m=0;m<2;++m){
        f32x4 s = {0.f,0.f,0.f,0.f};   // S^T: row k=n*16+4lg+r, col q=m*16+li
        s = __builtin_amdgcn_mfma_f32_16x16x32_bf16(bk0, aq[m][0], s, 0, 0, 0);
        s = __builtin_amdgcn_mfma_f32_16x16x32_bf16(bk1, aq[m][1], s, 0, 0, 0);
        uint2 pk;
        pk.x = cvtpk(__builtin_exp2f(s[0]), __builtin_exp2f(s[1]));
        pk.y = cvtpk(__builtin_exp2f(s[2]), __builtin_exp2f(s[3]));
        *(uint2*)(pW + (size_t)(m*16 + li)*PLD + n*16 + lg*4) = pk;
      }
    }
  };
  auto PV = [&](const char* sV, const u16* pR){
    bf16x8 pa0 = *(const bf16x8*)(pR + (size_t)(     li)*PLD + lg*8);
    bf16x8 pa1 = *(const bf16x8*)(pR + (size_t)(16 + li)*PLD + lg*8);
    __builtin_amdgcn_s_setprio(1);
    #pragma unroll
    for (int nd=0;nd<4;++nd){
      bf16x8 bv = *(const bf16x8*)(sV + (nd*16 + li)*64 + vc);
      o[0][nd] = __builtin_amdgcn_mfma_f32_16x16x32_bf16(pa0, bv, o[0][nd], 0, 0, 0);
      o[1][nd] = __builtin_amdgcn_mfma_f32_16x16x32_bf16(pa1, bv, o[1][nd], 0, 0, 0);
    }
    ls[0] = __builtin_amdgcn_mfma_f32_16x16x32_bf16(pa0, ones, ls[0], 0, 0, 0);
    ls[1] = __builtin_amdgcn_mfma_f32_16x16x32_bf16(pa1, ones, ls[1], 0, 0, 0);
    __builtin_amdgcn_s_setprio(0);
  };

  // prologue: stage K0,V0,K1; drain; barrier; P(0) -> pbuf0; barrier
  gload16(Kg + ksrc,          smem + ldst);
  gload16(Vg + vsrc0,         smem + 8192 + ldst);
  gload16(Kg + 4096u + ksrc,  smem + 4096 + ldst);
  asm volatile("s_waitcnt vmcnt(0)" ::: "memory");
  __builtin_amdgcn_s_barrier();
  QKEXP(smem, pw);                       // P(0) into copy 0
  __builtin_amdgcn_s_barrier();

  for (int kt = 0; kt < NKT-1; ++kt){
    const int pr = kt & 1, pn = pr ^ 1;
    // stage V(kt+1) -> Vbuf[pn], K(kt+2) -> Kbuf[pr]
    gload16(Vg + (kt+1)*64u + vsrc0, smem + 8192 + pn*4096 + ldst);
    if (kt + 2 < NKT)
      gload16(Kg + (kt+2)*4096u + ksrc, smem + pr*4096 + ldst);
    // QK(kt+1) from Kbuf[pn] -> P into pbuf[pn]; PV(kt) from pbuf[pr], Vbuf[pr]
    QKEXP(smem + pn*4096, pw + pn*1280);
    PV(smem + 8192 + pr*4096, pw + pr*1280);
    asm volatile("s_waitcnt vmcnt(0)" ::: "memory");
    __builtin_amdgcn_s_barrier();
  }
  PV(smem + 8192 + ((NKT-1)&1)*4096, pw + ((NKT-1)&1)*1280);   // PV(63)

  // store O [b*2048+t][h*64+d] bf16 (rowsum complete per lane/reg)
  const int b_ = bh >> 4, h = bh & 15;
  #pragma unroll
  for (int m=0;m<2;++m){
    #pragma unroll
    for (int r=0;r<4;++r){
      float linv = 1.0f / ls[m][r];
      int t = q0 + m*16 + lg*4 + r;
      #pragma unroll
      for (int nd=0;nd<4;++nd)
        O[((size_t)b_*2048 + t)*1024 + h*64 + nd*16 + li] = f2bf(o[m][nd][r] * linv);
    }
  }
}

// ---------- output projection (R8, XCD-affine) ----------
__global__ __launch_bounds__(256) void k_proj(const u16* __restrict__ O, const u16* __restrict__ wot,
                                              float* __restrict__ out){
  const int lane = threadIdx.x & 63, wv = threadIdx.x >> 6;
  const int lg = lane >> 4, li = lane & 15;
  const int blk = blockIdx.x;
  const int xcd = blk & 7, idx = blk >> 3;
  const int rowTile = (idx >> 3)*8 + xcd;
  const int colTile = idx & 7;
  const int row0 = rowTile*128 + wv*32;
  const int col0 = colTile*128;
  const int part = col0 >> 9;
  const int f0 = col0 & 511;

  f32x4 acc[2][8] = {};
  #pragma unroll 4
  for (int ks = 0; ks < 16; ++ks){
    bf16x8 a[2];
    #pragma unroll
    for (int m=0;m<2;++m)
      a[m] = *(const bf16x8*)(O + (size_t)(row0 + m*16 + li)*1024 + ks*64 + part*32 + lg*8);
    #pragma unroll
    for (int n=0;n<8;++n){
      bf16x8 b = *(const bf16x8*)(wot + (size_t)part*262144 + (size_t)(f0 + n*16 + li)*512 + ks*32 + lg*8);
      #pragma unroll
      for (int m=0;m<2;++m)
        acc[m][n] = __builtin_amdgcn_mfma_f32_16x16x32_bf16(a[m], b, acc[m][n], 0, 0, 0);
    }
  }
  float* ob = out + (size_t)part*(8192u*512u);
  #pragma unroll
  for (int m=0;m<2;++m)
    #pragma unroll
    for (int n=0;n<8;++n)
      #pragma unroll
      for (int r=0;r<4;++r)
        ob[(size_t)(row0 + m*16 + lg*4 + r)*512 + f0 + n*16 + li] = acc[m][n][r];
}

extern "C" void kernel_launch(void* const* d_in, const int* in_sizes, int n_in,
                              void* d_out, int out_size, void* d_ws, size_t ws_size,
                              hipStream_t stream){
  const float* x   = (const float*)d_in[0];
  const float* wqc = (const float*)d_in[1];
  const float* wqp = (const float*)d_in[2];
  const float* woc = (const float*)d_in[3];
  const float* wop = (const float*)d_in[4];

  char* ws = (char*)d_ws;
  u16* xb  = (u16*)(ws);
  u16* Q   = (u16*)(ws + 16777216);
  u16* K   = (u16*)(ws + 2*16777216);
  u16* VT  = (u16*)(ws + 3*16777216);
  u16* wqt = (u16*)(ws + 4*16777216);
  u16* wot = (u16*)(ws + 4*16777216 + 3145728);
  u16* O   = xb;   // xb dead after k_qkv
  float* out = (float*)d_out;

  k_cvt_x     <<<8192, 256, 0, stream>>>((const float4*)x, (uint2*)xb);
  k_repack_qkv<<<6144, 256, 0, stream>>>(wqc, wqp, wqt);
  k_repack_wo <<<2048, 256, 0, stream>>>(woc, wop, wot);
  k_qkv       <<<1024, 256, 0, stream>>>(xb, wqt, Q, K, VT);
  k_attn      <<<1024, 256, 0, stream>>>(Q, K, VT, O);
  k_proj      <<<512,  256, 0, stream>>>(O, wot, out);
}